// Round 9
// baseline (63.772 us; speedup 1.0000x reference)
//
#include <hip/hip_runtime.h>
#include <hip/hip_bf16.h>

typedef unsigned short ushort_t;
typedef __attribute__((ext_vector_type(8))) short s16x8;
typedef __attribute__((ext_vector_type(4))) float f32x4;

#define NB 8192
#define ND 128
#define ROWB 256            // bytes per bf16 row
#define NCLS 64
#define BMR 256             // rows per block (4 waves x 64)
#define WROWS 64
#define WCOLS 512           // cols per block
#define NSTEP 32            // 16-col steps per block
#define NGROUP (NB/16)      // 512 label groups
#define EPS 1e-8f
#define MARGIN 1.0f

__device__ __forceinline__ unsigned f2u(float f) {
    unsigned u = __float_as_uint(f);
    return (u & 0x80000000u) ? ~u : (u | 0x80000000u);
}
__device__ __forceinline__ float u2f(unsigned u) {
    return (u & 0x80000000u) ? __uint_as_float(u & 0x7fffffffu) : __uint_as_float(~u);
}

typedef const __attribute__((address_space(1))) void* gptr_t;
typedef __attribute__((address_space(3))) void* lptr_t;
__device__ __forceinline__ void gll16(const void* g, void* l) {
    __builtin_amdgcn_global_load_lds((gptr_t)g, (lptr_t)l, 16, 0, 0);
}

// ---- kernel 0: deterministic counting sort of rows by label (64 blocks) ----
__global__ void sort_kernel(const int* __restrict__ labels,
                            int* __restrict__ sortedIdx,
                            int* __restrict__ labS) {
    const int c = blockIdx.x;
    const int tid = threadIdx.x, lane = tid & 63, w = tid >> 6;
    __shared__ int wt[4];
    __shared__ int sbase;

    // start = #rows with label < c
    int lt = 0;
    for (int j = tid; j < NB; j += 256) lt += (labels[j] < c) ? 1 : 0;
    #pragma unroll
    for (int off = 32; off; off >>= 1) lt += __shfl_down(lt, off, 64);
    if (lane == 0) wt[w] = lt;
    __syncthreads();
    const int start = wt[0] + wt[1] + wt[2] + wt[3];
    if (tid == 0) sbase = 0;
    __syncthreads();

    // stable scatter of rows with label == c
    for (int chunk = 0; chunk < NB; chunk += 256) {
        const int j = chunk + tid;
        const bool f = (labels[j] == c);
        const unsigned long long m = __ballot(f);
        const int rank = __popcll(m & ((1ull << lane) - 1ull));
        if (lane == 0) wt[w] = __popcll(m);
        __syncthreads();
        if (f) {
            int wbase = 0;
            if (w > 0) wbase += wt[0];
            if (w > 1) wbase += wt[1];
            if (w > 2) wbase += wt[2];
            const int pos = start + sbase + wbase + rank;
            sortedIdx[pos] = j;
            labS[pos] = c;
        }
        __syncthreads();
        if (tid == 0) sbase += wt[0] + wt[1] + wt[2] + wt[3];
        __syncthreads();
    }
}

// ---- kernel 1: gather-permute + f32->bf16, group metadata, init sentinels ----
__global__ void prep_kernel(const float* __restrict__ E,
                            const int* __restrict__ sortedIdx,
                            const int* __restrict__ labS,
                            ushort_t* __restrict__ EbfS,
                            int* __restrict__ gLab,
                            unsigned* __restrict__ posU,
                            unsigned* __restrict__ negU) {
    const int tid  = threadIdx.x;
    const int lane = tid & 63;
    const int row  = blockIdx.x * 4 + (tid >> 6);
    const int old  = sortedIdx[row];

    const float2 v = reinterpret_cast<const float2*>(E + (size_t)old * ND)[lane];
    __hip_bfloat16 b0 = __float2bfloat16(v.x);
    __hip_bfloat16 b1 = __float2bfloat16(v.y);
    uint pk = (uint)*reinterpret_cast<ushort_t*>(&b0)
            | ((uint)*reinterpret_cast<ushort_t*>(&b1) << 16);
    reinterpret_cast<uint*>(EbfS + (size_t)row * ND)[lane] = pk;

    const int gid = blockIdx.x * 256 + tid;
    if (gid < NB) {
        posU[gid] = f2u(__builtin_inff());    // running min dot over positives
        negU[gid] = f2u(-__builtin_inff());   // running max dot over negatives
    }
    if (tid == 0 && blockIdx.x < NGROUP) {
        const int g = blockIdx.x;
        const int l0 = labS[g * 16];
        bool u = true;
        #pragma unroll
        for (int k = 1; k < 16; ++k) u = u && (labS[g * 16 + k] == l0);
        gLab[g] = u ? l0 : -1;
    }
}

// ---- kernel 2: sorted Gram fold; shared 3-buffer staging, 1 barrier/step ----
__global__ __launch_bounds__(256, 1) void triplet_gemm(
        const ushort_t* __restrict__ EbfS,
        const int* __restrict__ labS,
        const int* __restrict__ gLab,
        unsigned* __restrict__ posU,
        unsigned* __restrict__ negU) {
    __shared__ __align__(16) ushort_t Bb[3][16 * ND];   // 3 x 4 KB
    __shared__ __align__(16) int ldsLab[WCOLS];         // 2 KB
    __shared__ __align__(16) int ldsGL[NSTEP];          // 128 B

    const int tid = threadIdx.x, lane = tid & 63, w = tid >> 6;
    const int fr = lane & 15, fg = lane >> 4;
    const int wrow = blockIdx.x * BMR + w * WROWS;
    const int colBase = blockIdx.y * WCOLS;

    // chunk labels + group labels -> LDS
    ldsLab[tid]       = labS[colBase + tid];
    ldsLab[256 + tid] = labS[colBase + 256 + tid];
    if (tid < NSTEP) ldsGL[tid] = gLab[blockIdx.y * NSTEP + tid];

    // A fragments: 64 rows x K=128 from global (L2-hit)
    s16x8 a[4][4];
    #pragma unroll
    for (int ks = 0; ks < 4; ++ks)
        #pragma unroll
        for (int mi = 0; mi < 4; ++mi)
            a[ks][mi] = *reinterpret_cast<const s16x8*>(
                EbfS + (size_t)(wrow + mi * 16 + fr) * ND + ks * 32 + fg * 8);

    int labR[4][4];
    #pragma unroll
    for (int mi = 0; mi < 4; ++mi)
        #pragma unroll
        for (int reg = 0; reg < 4; ++reg)
            labR[mi][reg] = labS[wrow + mi * 16 + fg * 4 + reg];
    const int labLo = __builtin_amdgcn_readfirstlane(labS[wrow]);
    const int labHi = __builtin_amdgcn_readfirstlane(labS[wrow + WROWS - 1]);

    // staging: chunk tid -> tile row r=tid>>4, 16B slot s=tid&15, source-swizzled
    const int rS = tid >> 4, sS = tid & 15;
    const int srcOff = rS * ROWB + ((sS ^ (rS & 7)) << 4);
    auto stage = [&](int bi, int t) {
        const char* g = (const char*)EbfS + (size_t)(colBase + t * 16) * ROWB + srcOff;
        gll16(g, (char*)&Bb[bi][0] + tid * 16);
    };
    int rdOff[4];
    #pragma unroll
    for (int ks = 0; ks < 4; ++ks)
        rdOff[ks] = fr * ROWB + (((ks * 4 + fg) ^ (fr & 7)) << 4);

    stage(0, 0);
    asm volatile("s_waitcnt vmcnt(0)" ::: "memory");
    __syncthreads();

    const float PINF = __builtin_inff(), NINF = -__builtin_inff();
    f32x4 pv[4], nv[4];
    #pragma unroll
    for (int mi = 0; mi < 4; ++mi) {
        pv[mi] = f32x4{PINF, PINF, PINF, PINF};
        nv[mi] = f32x4{NINF, NINF, NINF, NINF};
    }
    const f32x4 zf = {0.f, 0.f, 0.f, 0.f};

    #pragma unroll 1
    for (int t = 0; t < NSTEP; ++t) {
        if (t + 1 < NSTEP) {
            stage((t + 1) % 3, t + 1);
            asm volatile("s_waitcnt vmcnt(1)" ::: "memory");   // my stage(t) landed
        } else {
            asm volatile("s_waitcnt vmcnt(0)" ::: "memory");
        }
        __builtin_amdgcn_s_barrier();                           // everyone's stage(t) landed

        const char* cp = (const char*)&Bb[t % 3][0];
        s16x8 b[4];
        #pragma unroll
        for (int ks = 0; ks < 4; ++ks)
            b[ks] = *reinterpret_cast<const s16x8*>(cp + rdOff[ks]);

        f32x4 acc[4];
        #pragma unroll
        for (int mi = 0; mi < 4; ++mi)
            acc[mi] = __builtin_amdgcn_mfma_f32_16x16x32_bf16(a[0][mi], b[0], zf, 0, 0, 0);
        #pragma unroll
        for (int ks = 1; ks < 4; ++ks)
            #pragma unroll
            for (int mi = 0; mi < 4; ++mi)
                acc[mi] = __builtin_amdgcn_mfma_f32_16x16x32_bf16(a[ks][mi], b[ks], acc[mi], 0, 0, 0);

        const int gl = __builtin_amdgcn_readfirstlane(ldsGL[t]);
        if (gl >= 0) {
            if (gl < labLo || gl > labHi) {
                // uniform group, no row matches: pure negatives -> 1 op/elem
                #pragma unroll
                for (int mi = 0; mi < 4; ++mi)
                    #pragma unroll
                    for (int reg = 0; reg < 4; ++reg)
                        nv[mi][reg] = fmaxf(nv[mi][reg], acc[mi][reg]);
            } else {
                // uniform group, label in this wave's range: scalar-compare fold
                #pragma unroll
                for (int mi = 0; mi < 4; ++mi)
                    #pragma unroll
                    for (int reg = 0; reg < 4; ++reg) {
                        const bool eq = (labR[mi][reg] == gl);
                        pv[mi][reg] = fminf(pv[mi][reg], eq ? acc[mi][reg] : PINF);
                        nv[mi][reg] = fmaxf(nv[mi][reg], eq ? NINF : acc[mi][reg]);
                    }
            }
        } else {
            // mixed (class-boundary) group: per-lane column label
            const int labC = ldsLab[t * 16 + fr];
            #pragma unroll
            for (int mi = 0; mi < 4; ++mi)
                #pragma unroll
                for (int reg = 0; reg < 4; ++reg) {
                    const bool eq = (labR[mi][reg] == labC);
                    pv[mi][reg] = fminf(pv[mi][reg], eq ? acc[mi][reg] : PINF);
                    nv[mi][reg] = fmaxf(nv[mi][reg], eq ? NINF : acc[mi][reg]);
                }
        }
    }

    // epilogue: 16-lane reduce, 2 atomics per row from fr==0 lanes
    #pragma unroll
    for (int mi = 0; mi < 4; ++mi)
        #pragma unroll
        for (int reg = 0; reg < 4; ++reg) {
            float p = pv[mi][reg], n = nv[mi][reg];
            #pragma unroll
            for (int off = 1; off < 16; off <<= 1) {
                p = fminf(p, __shfl_xor(p, off, 64));
                n = fmaxf(n, __shfl_xor(n, off, 64));
            }
            if (fr == 0) {
                const int grow = wrow + mi * 16 + fg * 4 + reg;
                atomicMin(&posU[grow], f2u(p));
                atomicMax(&negU[grow], f2u(n));
            }
        }
}

// ---- kernel 3: single-block deterministic finalize (|e|^2 == 1) ----
__global__ void finalize_kernel(const unsigned* __restrict__ posU,
                                const unsigned* __restrict__ negU,
                                float* __restrict__ out) {
    __shared__ float sl[16], sc[16];
    const int tid = threadIdx.x, lane = tid & 63, w = tid >> 6;

    float lsum = 0.f, csum = 0.f;
    #pragma unroll
    for (int k = 0; k < NB / 1024; ++k) {
        const int i = k * 1024 + tid;
        float pMin = u2f(posU[i]);
        float nMax = u2f(negU[i]);
        bool valid = (pMin < 2.0f) && (nMax > -2.0f);
        float pd = sqrtf(fmaxf(2.0f - 2.0f * pMin, 0.f) + EPS);
        float nd = sqrtf(fmaxf(2.0f - 2.0f * nMax, 0.f) + EPS);
        float l  = fmaxf(pd - nd + MARGIN, 0.f);
        if (valid) { lsum += l; csum += 1.f; }
    }
    #pragma unroll
    for (int off = 32; off; off >>= 1) {
        lsum += __shfl_down(lsum, off, 64);
        csum += __shfl_down(csum, off, 64);
    }
    if (lane == 0) { sl[w] = lsum; sc[w] = csum; }
    __syncthreads();
    if (tid == 0) {
        float L = 0.f, C = 0.f;
        #pragma unroll
        for (int k = 0; k < 16; ++k) { L += sl[k]; C += sc[k]; }
        out[0] = (C > 0.f) ? (L / C) : 0.f;
        out[1] = C;
    }
}

extern "C" void kernel_launch(void* const* d_in, const int* in_sizes, int n_in,
                              void* d_out, int out_size, void* d_ws, size_t ws_size,
                              hipStream_t stream) {
    const float* E      = (const float*)d_in[0];
    const int*   labels = (const int*)d_in[1];
    float*       out    = (float*)d_out;

    char* ws = (char*)d_ws;
    size_t off = 0;
    ushort_t* EbfS  = (ushort_t*)(ws + off);  off += (size_t)NB * ND * 2;  // 2 MiB
    unsigned* posU  = (unsigned*)(ws + off);  off += (size_t)NB * 4;
    unsigned* negU  = (unsigned*)(ws + off);  off += (size_t)NB * 4;
    int*      sIdx  = (int*)(ws + off);       off += (size_t)NB * 4;
    int*      labS  = (int*)(ws + off);       off += (size_t)NB * 4;
    int*      gLab  = (int*)(ws + off);       off += (size_t)NGROUP * 4;

    sort_kernel<<<NCLS, 256, 0, stream>>>(labels, sIdx, labS);
    prep_kernel<<<NB / 4, 256, 0, stream>>>(E, sIdx, labS, EbfS, gLab, posU, negU);

    dim3 grid(NB / BMR, NB / WCOLS);
    triplet_gemm<<<grid, 256, 0, stream>>>(EbfS, labS, gLab, posU, negU);

    finalize_kernel<<<1, 1024, 0, stream>>>(posU, negU, out);
}

// Round 10
// 48.095 us; speedup vs baseline: 1.3259x; 1.3259x over previous
//
#include <hip/hip_runtime.h>
#include <hip/hip_bf16.h>

typedef unsigned short ushort_t;
typedef __attribute__((ext_vector_type(8))) short s16x8;
typedef __attribute__((ext_vector_type(4))) float f32x4;

#define NB 8192
#define ND 128
#define ROWB 256            // bytes per bf16 row
#define NCLS 64
#define BMR 256             // rows per block (4 waves x 64)
#define WROWS 64
#define WCOLS 512           // cols per block
#define TCOLS 128           // cols staged per period
#define NPER 4              // periods per block
#define NGROUP (NB/16)      // 512 label groups
#define EPS 1e-8f
#define MARGIN 1.0f

__device__ __forceinline__ unsigned f2u(float f) {
    unsigned u = __float_as_uint(f);
    return (u & 0x80000000u) ? ~u : (u | 0x80000000u);
}
__device__ __forceinline__ float u2f(unsigned u) {
    return (u & 0x80000000u) ? __uint_as_float(u & 0x7fffffffu) : __uint_as_float(~u);
}

typedef const __attribute__((address_space(1))) void* gptr_t;
typedef __attribute__((address_space(3))) void* lptr_t;
__device__ __forceinline__ void gll16(const void* g, void* l) {
    __builtin_amdgcn_global_load_lds((gptr_t)g, (lptr_t)l, 16, 0, 0);
}

// ---- kernel 0: counting sort by label; 64 blocks, 4 waves, 1 barrier ----
__global__ void sort_kernel(const int* __restrict__ labels,
                            int* __restrict__ sortedIdx,
                            int* __restrict__ labS) {
    const int c = blockIdx.x;
    const int tid = threadIdx.x, lane = tid & 63, w = tid >> 6;
    __shared__ int qcnt[4], qlt[4];

    int cnt = 0, lt = 0;
    #pragma unroll 4
    for (int it = 0; it < 32; ++it) {
        const int L = labels[w * 2048 + it * 64 + lane];
        cnt += (L == c);
        lt  += (L < c);
    }
    #pragma unroll
    for (int off = 32; off; off >>= 1) {
        cnt += __shfl_down(cnt, off, 64);
        lt  += __shfl_down(lt, off, 64);
    }
    if (lane == 0) { qcnt[w] = cnt; qlt[w] = lt; }
    __syncthreads();

    int base = qlt[0] + qlt[1] + qlt[2] + qlt[3];
    if (w > 0) base += qcnt[0];
    if (w > 1) base += qcnt[1];
    if (w > 2) base += qcnt[2];

    for (int it = 0; it < 32; ++it) {
        const int j = w * 2048 + it * 64 + lane;
        const bool f = (labels[j] == c);
        const unsigned long long m = __ballot(f);
        if (f) {
            const int pos = base + __popcll(m & ((1ull << lane) - 1ull));
            sortedIdx[pos] = j;
            labS[pos] = c;
        }
        base += __popcll(m);
    }
}

// ---- kernel 1: gather-permute + f32->bf16, group metadata, init sentinels ----
__global__ void prep_kernel(const float* __restrict__ E,
                            const int* __restrict__ sortedIdx,
                            const int* __restrict__ labS,
                            ushort_t* __restrict__ EbfS,
                            int* __restrict__ gLab,
                            unsigned* __restrict__ posU,
                            unsigned* __restrict__ negU) {
    const int tid  = threadIdx.x;
    const int lane = tid & 63;
    const int row  = blockIdx.x * 4 + (tid >> 6);
    const int old  = sortedIdx[row];

    const float2 v = reinterpret_cast<const float2*>(E + (size_t)old * ND)[lane];
    __hip_bfloat16 b0 = __float2bfloat16(v.x);
    __hip_bfloat16 b1 = __float2bfloat16(v.y);
    uint pk = (uint)*reinterpret_cast<ushort_t*>(&b0)
            | ((uint)*reinterpret_cast<ushort_t*>(&b1) << 16);
    reinterpret_cast<uint*>(EbfS + (size_t)row * ND)[lane] = pk;

    const int gid = blockIdx.x * 256 + tid;
    if (gid < NB) {
        posU[gid] = f2u(__builtin_inff());
        negU[gid] = f2u(-__builtin_inff());
    }
    if (tid == 0 && blockIdx.x < NGROUP) {
        const int g = blockIdx.x;
        const int l0 = labS[g * 16];
        bool u = true;
        #pragma unroll
        for (int k = 1; k < 16; ++k) u = u && (labS[g * 16 + k] == l0);
        gLab[g] = u ? l0 : -1;
    }
}

// ---- kernel 2: 128-col periods, 1 barrier/period, precomputed branch mask ----
__global__ __launch_bounds__(256, 2) void triplet_gemm(
        const ushort_t* __restrict__ EbfS,
        const int* __restrict__ labS,
        const int* __restrict__ gLab,
        unsigned* __restrict__ posU,
        unsigned* __restrict__ negU) {
    __shared__ __align__(16) ushort_t Bb[2][TCOLS * ND];   // 2 x 32 KB
    __shared__ __align__(16) int ldsLab[WCOLS];            // 2 KB
    __shared__ __align__(16) int ldsGL[32];                // 128 B

    const int tid = threadIdx.x, lane = tid & 63, w = tid >> 6;
    const int fr = lane & 15, fg = lane >> 4;
    const int wrow = blockIdx.x * BMR + w * WROWS;
    const int colBase = blockIdx.y * WCOLS;

    ldsLab[tid]       = labS[colBase + tid];
    ldsLab[256 + tid] = labS[colBase + 256 + tid];
    if (tid < 32) ldsGL[tid] = gLab[blockIdx.y * 32 + tid];

    // A fragments: 64 rows x K=128 (L2-hit gathers)
    s16x8 a[4][4];
    #pragma unroll
    for (int ks = 0; ks < 4; ++ks)
        #pragma unroll
        for (int mi = 0; mi < 4; ++mi)
            a[ks][mi] = *reinterpret_cast<const s16x8*>(
                EbfS + (size_t)(wrow + mi * 16 + fr) * ND + ks * 32 + fg * 8);

    // packed row labels (4 per int)
    int labPk[4];
    #pragma unroll
    for (int mi = 0; mi < 4; ++mi) {
        const int4 lr = *reinterpret_cast<const int4*>(&labS[wrow + mi * 16 + fg * 4]);
        labPk[mi] = lr.x | (lr.y << 8) | (lr.z << 16) | (lr.w << 24);
    }
    const int labLo = __builtin_amdgcn_readfirstlane(labS[wrow]);
    const int labHi = __builtin_amdgcn_readfirstlane(labS[wrow + WROWS - 1]);

    // staging offsets: chunk c = it*256+tid -> row r=c>>4, slot s=c&15, swizzled src
    int srcOff[8];
    #pragma unroll
    for (int it = 0; it < 8; ++it) {
        const int c = it * 256 + tid;
        const int r = c >> 4, s = c & 15;
        srcOff[it] = r * ROWB + ((s ^ (r & 7)) << 4);
    }
    auto stage = [&](int bi, int t) {
        const char* g = (const char*)EbfS + ((size_t)colBase + (size_t)t * TCOLS) * ROWB;
        char* l = (char*)&Bb[bi][0];
        #pragma unroll
        for (int it = 0; it < 8; ++it)
            gll16(g + srcOff[it], l + it * 4096 + (tid << 4));
    };
    int rdOff[4];
    #pragma unroll
    for (int ks = 0; ks < 4; ++ks)
        rdOff[ks] = fr * ROWB + (((ks * 4 + fg) ^ (fr & 7)) << 4);

    stage(0, 0);
    __syncthreads();    // drains stage(0) + ldsLab/ldsGL visible

    // per-wave substep category mask: bit s = uniform group outside wave's range
    unsigned negMask;
    {
        const int s = lane & 31;
        const int gl = ldsGL[s];
        const bool pureNeg = (gl >= 0) && (gl < labLo || gl > labHi);
        negMask = (unsigned)(__ballot(pureNeg) & 0xFFFFFFFFull);
    }

    const float PINF = __builtin_inff(), NINF = -__builtin_inff();
    f32x4 pv[4], nv[4];
    #pragma unroll
    for (int mi = 0; mi < 4; ++mi) {
        pv[mi] = f32x4{PINF, PINF, PINF, PINF};
        nv[mi] = f32x4{NINF, NINF, NINF, NINF};
    }
    const f32x4 zf = {0.f, 0.f, 0.f, 0.f};

    #pragma unroll 1
    for (int p = 0; p < NPER; ++p) {
        if (p + 1 < NPER) stage((p + 1) & 1, p + 1);
        const char* cp = (const char*)&Bb[p & 1][0];
        const unsigned pm = negMask >> (p * 8);

        auto loadB = [&](s16x8* b, int ss) {
            const char* sp = cp + ss * 4096;
            #pragma unroll
            for (int ks = 0; ks < 4; ++ks)
                b[ks] = *reinterpret_cast<const s16x8*>(sp + rdOff[ks]);
        };
        auto compute = [&](const s16x8* b, int ss) {
            f32x4 acc[4];
            #pragma unroll
            for (int mi = 0; mi < 4; ++mi)
                acc[mi] = __builtin_amdgcn_mfma_f32_16x16x32_bf16(a[0][mi], b[0], zf, 0, 0, 0);
            #pragma unroll
            for (int ks = 1; ks < 4; ++ks)
                #pragma unroll
                for (int mi = 0; mi < 4; ++mi)
                    acc[mi] = __builtin_amdgcn_mfma_f32_16x16x32_bf16(a[ks][mi], b[ks], acc[mi], 0, 0, 0);

            if ((pm >> ss) & 1) {          // pure negatives: 1 op/elem
                #pragma unroll
                for (int mi = 0; mi < 4; ++mi)
                    #pragma unroll
                    for (int reg = 0; reg < 4; ++reg)
                        nv[mi][reg] = fmaxf(nv[mi][reg], acc[mi][reg]);
            } else {                        // own-class or mixed group
                const int labC = ldsLab[(p * 8 + ss) * 16 + fr];
                #pragma unroll
                for (int mi = 0; mi < 4; ++mi)
                    #pragma unroll
                    for (int reg = 0; reg < 4; ++reg) {
                        const bool eq = (((labPk[mi] >> (reg * 8)) & 255) == labC);
                        pv[mi][reg] = fminf(pv[mi][reg], eq ? acc[mi][reg] : PINF);
                        nv[mi][reg] = fmaxf(nv[mi][reg], eq ? NINF : acc[mi][reg]);
                    }
            }
        };

        s16x8 bX[4], bY[4];
        loadB(bX, 0);
        loadB(bY, 1); compute(bX, 0);
        loadB(bX, 2); compute(bY, 1);
        loadB(bY, 3); compute(bX, 2);
        loadB(bX, 4); compute(bY, 3);
        loadB(bY, 5); compute(bX, 4);
        loadB(bX, 6); compute(bY, 5);
        loadB(bY, 7); compute(bX, 6);
        compute(bY, 7);

        if (p + 1 < NPER) __syncthreads();   // drain my stage(p+1), sync buffers
    }

    // epilogue: 16-lane reduce, 2 atomics per row from fr==0 lanes
    #pragma unroll
    for (int mi = 0; mi < 4; ++mi)
        #pragma unroll
        for (int reg = 0; reg < 4; ++reg) {
            float p = pv[mi][reg], n = nv[mi][reg];
            #pragma unroll
            for (int off = 1; off < 16; off <<= 1) {
                p = fminf(p, __shfl_xor(p, off, 64));
                n = fmaxf(n, __shfl_xor(n, off, 64));
            }
            if (fr == 0) {
                const int grow = wrow + mi * 16 + fg * 4 + reg;
                atomicMin(&posU[grow], f2u(p));
                atomicMax(&negU[grow], f2u(n));
            }
        }
}

// ---- kernel 3: single-block deterministic finalize (|e|^2 == 1) ----
__global__ void finalize_kernel(const unsigned* __restrict__ posU,
                                const unsigned* __restrict__ negU,
                                float* __restrict__ out) {
    __shared__ float sl[16], sc[16];
    const int tid = threadIdx.x, lane = tid & 63, w = tid >> 6;

    float lsum = 0.f, csum = 0.f;
    #pragma unroll
    for (int k = 0; k < NB / 1024; ++k) {
        const int i = k * 1024 + tid;
        float pMin = u2f(posU[i]);
        float nMax = u2f(negU[i]);
        bool valid = (pMin < 2.0f) && (nMax > -2.0f);
        float pd = sqrtf(fmaxf(2.0f - 2.0f * pMin, 0.f) + EPS);
        float nd = sqrtf(fmaxf(2.0f - 2.0f * nMax, 0.f) + EPS);
        float l  = fmaxf(pd - nd + MARGIN, 0.f);
        if (valid) { lsum += l; csum += 1.f; }
    }
    #pragma unroll
    for (int off = 32; off; off >>= 1) {
        lsum += __shfl_down(lsum, off, 64);
        csum += __shfl_down(csum, off, 64);
    }
    if (lane == 0) { sl[w] = lsum; sc[w] = csum; }
    __syncthreads();
    if (tid == 0) {
        float L = 0.f, C = 0.f;
        #pragma unroll
        for (int k = 0; k < 16; ++k) { L += sl[k]; C += sc[k]; }
        out[0] = (C > 0.f) ? (L / C) : 0.f;
        out[1] = C;
    }
}

extern "C" void kernel_launch(void* const* d_in, const int* in_sizes, int n_in,
                              void* d_out, int out_size, void* d_ws, size_t ws_size,
                              hipStream_t stream) {
    const float* E      = (const float*)d_in[0];
    const int*   labels = (const int*)d_in[1];
    float*       out    = (float*)d_out;

    char* ws = (char*)d_ws;
    size_t off = 0;
    ushort_t* EbfS  = (ushort_t*)(ws + off);  off += (size_t)NB * ND * 2;  // 2 MiB
    unsigned* posU  = (unsigned*)(ws + off);  off += (size_t)NB * 4;
    unsigned* negU  = (unsigned*)(ws + off);  off += (size_t)NB * 4;
    int*      sIdx  = (int*)(ws + off);       off += (size_t)NB * 4;
    int*      labS  = (int*)(ws + off);       off += (size_t)NB * 4;
    int*      gLab  = (int*)(ws + off);       off += (size_t)NGROUP * 4;

    sort_kernel<<<NCLS, 256, 0, stream>>>(labels, sIdx, labS);
    prep_kernel<<<NB / 4, 256, 0, stream>>>(E, sIdx, labS, EbfS, gLab, posU, negU);

    dim3 grid(NB / BMR, NB / WCOLS);
    triplet_gemm<<<grid, 256, 0, stream>>>(EbfS, labS, gLab, posU, negU);

    finalize_kernel<<<1, 1024, 0, stream>>>(posU, negU, out);
}